// Round 8
// baseline (776.675 us; speedup 1.0000x reference)
//
#include <hip/hip_runtime.h>
#include <hip/hip_bf16.h>

#define HID 2048
#define NH 20
#define QR 768
#define KVR 512
#define DN 192
#define DR 64
#define DV 256
#define HD 256          // HEAD_DIM = DN + DR
#define S_LEN 2048
#define HKV 448         // DN + DV
#define KV_N (NH * HKV) // 8960
#define Q_N (NH * HD)   // 5120
#define O_N (NH * DV)   // 5120
#define KVA_N (KVR + DR) // 576
#define KVAP 640         // padded kv_a rows
#define QKVA (QR + KVAP) // 1408 fused a-proj cols

typedef short bf16x8 __attribute__((ext_vector_type(8)));
typedef short bf16x4 __attribute__((ext_vector_type(4)));
typedef float f32x4 __attribute__((ext_vector_type(4)));

__device__ inline short f2bs(float f) {
  __hip_bfloat16 h = __float2bfloat16(f);
  return *reinterpret_cast<short*>(&h);
}
__device__ inline float bs2f(short s) {
  __hip_bfloat16 h = *reinterpret_cast<__hip_bfloat16*>(&s);
  return __bfloat162float(h);
}

__device__ inline void gload16(const void* g, void* l) {
  __builtin_amdgcn_global_load_lds((const __attribute__((address_space(1))) void*)g,
                                   (__attribute__((address_space(3))) void*)l, 16, 0, 0);
}

#define WAIT_LGKM0() asm volatile("s_waitcnt lgkmcnt(0)" ::: "memory")
#define WAIT_VM0() asm volatile("s_waitcnt vmcnt(0)" ::: "memory")

// ---------------- fp32 -> bf16 convert ----------------
__global__ void f2b_kernel(const float* __restrict__ in, short* __restrict__ out, size_t n) {
  size_t i = (size_t)blockIdx.x * blockDim.x + threadIdx.x;
  size_t stride = (size_t)gridDim.x * blockDim.x;
  for (; i < n; i += stride) out[i] = f2bs(in[i]);
}

// ---------------- big GEMM: 128x128 tile, BK=64, global_load_lds + XOR swizzle ----------------
template <int OUT_BF16>
__global__ __launch_bounds__(256) void gemm128(const short* __restrict__ A,
                                               const short* __restrict__ B,
                                               void* __restrict__ Cp,
                                               int M, int N, int K) {
  __shared__ alignas(16) short As[128 * 64];
  __shared__ alignas(16) short Bs[128 * 64];
  int tid = threadIdx.x;
  int w = tid >> 6, l = tid & 63;
  int lr = l & 15, lg = l >> 4;
  int wr = w >> 1, wc = w & 1;
  int row0 = blockIdx.y * 128, col0 = blockIdx.x * 128;
  f32x4 acc[4][4] = {};
  for (int k0 = 0; k0 < K; k0 += 64) {
    if (k0) __syncthreads();
#pragma unroll
    for (int p = 0; p < 4; ++p) {
      int c = p * 256 + tid;
      int row = c >> 3;
      int sb = ((c & 7) * 16) ^ ((row & 7) << 4);
      gload16((const char*)A + ((size_t)(row0 + row) * K + k0) * 2 + sb, (char*)As + c * 16);
      gload16((const char*)B + ((size_t)(col0 + row) * K + k0) * 2 + sb, (char*)Bs + c * 16);
    }
    __syncthreads();
    bf16x8 af[4][2], bf[4][2];
#pragma unroll
    for (int m = 0; m < 4; ++m)
#pragma unroll
      for (int kk = 0; kk < 2; ++kk) {
        int ra = wr * 64 + m * 16 + lr;
        int rb = wc * 64 + m * 16 + lr;
        int cb = kk * 64 + lg * 16;
        af[m][kk] = *(const bf16x8*)((const char*)As + ra * 128 + (cb ^ ((ra & 7) << 4)));
        bf[m][kk] = *(const bf16x8*)((const char*)Bs + rb * 128 + (cb ^ ((rb & 7) << 4)));
      }
#pragma unroll
    for (int m = 0; m < 4; ++m)
#pragma unroll
      for (int n = 0; n < 4; ++n) {
        acc[m][n] = __builtin_amdgcn_mfma_f32_16x16x32_bf16(af[m][0], bf[n][0], acc[m][n], 0, 0, 0);
        acc[m][n] = __builtin_amdgcn_mfma_f32_16x16x32_bf16(af[m][1], bf[n][1], acc[m][n], 0, 0, 0);
      }
  }
#pragma unroll
  for (int m = 0; m < 4; ++m)
#pragma unroll
    for (int n = 0; n < 4; ++n)
#pragma unroll
      for (int r = 0; r < 4; ++r) {
        int row = row0 + wr * 64 + m * 16 + lg * 4 + r;
        int col = col0 + wc * 64 + n * 16 + lr;
        if (OUT_BF16)
          ((short*)Cp)[(size_t)row * N + col] = f2bs(acc[m][n][r]);
        else
          ((float*)Cp)[(size_t)row * N + col] = acc[m][n][r];
      }
}

// ---------------- medium GEMM: 64x128 tile (for wide-short shapes) ----------------
__global__ __launch_bounds__(256) void gemm64(const short* __restrict__ A,
                                              const short* __restrict__ B,
                                              float* __restrict__ C,
                                              int M, int N, int K) {
  __shared__ alignas(16) short As[64 * 64];    // 8KB
  __shared__ alignas(16) short Bs[128 * 64];   // 16KB
  int tid = threadIdx.x;
  int w = tid >> 6, l = tid & 63;
  int lr = l & 15, lg = l >> 4;
  int wr = w >> 1, wc = w & 1;
  int row0 = blockIdx.y * 64, col0 = blockIdx.x * 128;
  f32x4 acc[2][4] = {};
  for (int k0 = 0; k0 < K; k0 += 64) {
    if (k0) __syncthreads();
#pragma unroll
    for (int p = 0; p < 2; ++p) {
      int c = p * 256 + tid;
      int row = c >> 3;
      int sb = ((c & 7) * 16) ^ ((row & 7) << 4);
      gload16((const char*)A + ((size_t)(row0 + row) * K + k0) * 2 + sb, (char*)As + c * 16);
    }
#pragma unroll
    for (int p = 0; p < 4; ++p) {
      int c = p * 256 + tid;
      int row = c >> 3;
      int sb = ((c & 7) * 16) ^ ((row & 7) << 4);
      gload16((const char*)B + ((size_t)(col0 + row) * K + k0) * 2 + sb, (char*)Bs + c * 16);
    }
    __syncthreads();
    bf16x8 af[2][2], bf[4][2];
#pragma unroll
    for (int m = 0; m < 2; ++m)
#pragma unroll
      for (int kk = 0; kk < 2; ++kk) {
        int ra = wr * 32 + m * 16 + lr;
        int cb = kk * 64 + lg * 16;
        af[m][kk] = *(const bf16x8*)((const char*)As + ra * 128 + (cb ^ ((ra & 7) << 4)));
      }
#pragma unroll
    for (int n = 0; n < 4; ++n)
#pragma unroll
      for (int kk = 0; kk < 2; ++kk) {
        int rb = wc * 64 + n * 16 + lr;
        int cb = kk * 64 + lg * 16;
        bf[n][kk] = *(const bf16x8*)((const char*)Bs + rb * 128 + (cb ^ ((rb & 7) << 4)));
      }
#pragma unroll
    for (int m = 0; m < 2; ++m)
#pragma unroll
      for (int n = 0; n < 4; ++n) {
        acc[m][n] = __builtin_amdgcn_mfma_f32_16x16x32_bf16(af[m][0], bf[n][0], acc[m][n], 0, 0, 0);
        acc[m][n] = __builtin_amdgcn_mfma_f32_16x16x32_bf16(af[m][1], bf[n][1], acc[m][n], 0, 0, 0);
      }
  }
#pragma unroll
  for (int m = 0; m < 2; ++m)
#pragma unroll
    for (int n = 0; n < 4; ++n)
#pragma unroll
      for (int r = 0; r < 4; ++r) {
        int row = row0 + wr * 32 + m * 16 + lg * 4 + r;
        int col = col0 + wc * 64 + n * 16 + lr;
        C[(size_t)row * N + col] = acc[m][n][r];
      }
}

// ---------------- rmsnorm (fp32 in, bf16 out) ----------------
__global__ __launch_bounds__(256) void rmsnorm_kernel(const float* __restrict__ in,
                                                      const float* __restrict__ w,
                                                      short* __restrict__ out,
                                                      int N, int in_stride, int out_stride) {
  int row = blockIdx.x;
  const float* x = in + (size_t)row * in_stride;
  float ss = 0.f;
  for (int i = threadIdx.x; i < N; i += 256) { float v = x[i]; ss += v * v; }
#pragma unroll
  for (int off = 32; off >= 1; off >>= 1) ss += __shfl_down(ss, off);
  __shared__ float red[4];
  if ((threadIdx.x & 63) == 0) red[threadIdx.x >> 6] = ss;
  __syncthreads();
  float tot = red[0] + red[1] + red[2] + red[3];
  float sc = rsqrtf(tot / (float)N + 1e-5f);
  short* o = out + (size_t)row * out_stride;
  for (int i = threadIdx.x; i < N; i += 256) o[i] = f2bs(x[i] * sc * w[i]);
}

// ---------------- rope tables ----------------
__global__ void rope_table_kernel(const int* __restrict__ pos, float* __restrict__ ct,
                                  float* __restrict__ st) {
  int s = blockIdx.x * blockDim.x + threadIdx.x;
  if (s >= S_LEN) return;
  double p = (double)pos[s];
  for (int d = 0; d < 32; ++d) {
    double invf = exp(-((double)(2 * d) / 64.0) * log(1.0e6));
    double a = p * invf;
    ct[s * 32 + d] = (float)cos(a);
    st[s * 32 + d] = (float)sin(a);
  }
}

// ---------------- rope applied in-place to q's rope slice ----------------
__global__ void rope_q_kernel(short* __restrict__ q, const float* __restrict__ ct,
                              const float* __restrict__ st) {
  int idx = blockIdx.x * blockDim.x + threadIdx.x;
  if (idx >= S_LEN * NH) return;
  int s = idx / NH, h = idx % NH;
  short* p = q + (size_t)s * Q_N + h * HD + DN;
  float x[64];
#pragma unroll
  for (int i = 0; i < 64; ++i) x[i] = bs2f(p[i]);
  const float* c = ct + s * 32;
  const float* sn = st + s * 32;
#pragma unroll
  for (int d = 0; d < 32; ++d) {
    float x1 = x[2 * d], x2 = x[2 * d + 1];
    p[d] = f2bs(x1 * c[d] - x2 * sn[d]);
    p[32 + d] = f2bs(x1 * sn[d] + x2 * c[d]);
  }
}

// ---------------- rope for shared k_rope (reads fused qkv buffer) ----------------
__global__ void rope_k_kernel(const float* __restrict__ base, const float* __restrict__ ct,
                              const float* __restrict__ st, short* __restrict__ kr) {
  int s = blockIdx.x * blockDim.x + threadIdx.x;
  if (s >= S_LEN) return;
  const float* x = base + (size_t)s * QKVA;
  const float* c = ct + s * 32;
  const float* sn = st + s * 32;
  short* o = kr + s * 64;
#pragma unroll
  for (int d = 0; d < 32; ++d) {
    float x1 = x[2 * d], x2 = x[2 * d + 1];
    o[d] = f2bs(x1 * c[d] - x2 * sn[d]);
    o[32 + d] = f2bs(x1 * sn[d] + x2 * c[d]);
  }
}

// ---------------- build Kc[h][s][256] = k_nope ‖ roped k_rope ----------------
__global__ void kc_build(const short* __restrict__ kvx, const short* __restrict__ kr,
                         short* __restrict__ kc) {
  int idx = blockIdx.x * 256 + threadIdx.x;
  int h = idx >> 16;
  int r = idx & 65535;
  int s = r >> 5, c = r & 31;
  const short* src = (c < 24) ? kvx + (size_t)s * KV_N + h * HKV + c * 8
                              : kr + (size_t)s * 64 + (c - 24) * 8;
  *(bf16x8*)(kc + ((size_t)h * S_LEN + s) * HD + c * 8) = *(const bf16x8*)src;
}

// ---------------- transpose V with PV-key permutation: vtg[h][d][key-perm] ----------------
// Within each 32-key block, position p holds key kappa(p) = (p&4)? 16+(p>>3)*4+(p&3)
//                                                          : (p>>3)*4+(p&3),
// matching the swapped-QK^T A-fragment key order (lane lg holds keys lg*4+{0..3} and
// 16+lg*4+{0..3}) so a PV B-frag is ONE contiguous 16B read at key0 + lg*8.
__global__ __launch_bounds__(256) void vtrans(const short* __restrict__ kvx,
                                              short* __restrict__ vtg) {
  __shared__ short tile[64][65];
  int s0 = blockIdx.x * 64, d0 = blockIdx.y * 64, h = blockIdx.z;
  int tid = threadIdx.x;
#pragma unroll
  for (int p = 0; p < 2; ++p) {
    int s = p * 32 + (tid >> 3), dc = (tid & 7) * 8;
    bf16x8 v = *(const bf16x8*)(kvx + (size_t)(s0 + s) * KV_N + h * HKV + DN + d0 + dc);
#pragma unroll
    for (int j = 0; j < 8; ++j) tile[s][dc + j] = v[j];
  }
  __syncthreads();
#pragma unroll
  for (int p = 0; p < 2; ++p) {
    int d = p * 32 + (tid >> 3), sc = (tid & 7) * 8;
    bf16x4 a, b;
#pragma unroll
    for (int j = 0; j < 4; ++j) a[j] = tile[sc + j][d];
#pragma unroll
    for (int j = 0; j < 4; ++j) b[j] = tile[sc + 4 + j][d];
    int q1 = sc & 31, q2 = q1 + 4;           // kappa-quads (q1 in {0,8,16,24})
    int p1 = (q1 < 16) ? (q1 >> 2) * 8 : ((q1 - 16) >> 2) * 8 + 4;
    int p2 = (q2 < 16) ? (q2 >> 2) * 8 : ((q2 - 16) >> 2) * 8 + 4;
    size_t rowbase = ((size_t)h * DV + d0 + d) * S_LEN + s0 + (sc & ~31);
    *(bf16x4*)(vtg + rowbase + p1) = a;
    *(bf16x4*)(vtg + rowbase + p2) = b;
  }
}

// ---------------- fused flash attention v7: swapped QK^T, V direct-from-global ----------------
// grid = 640 (XCD-swizzled); 256 thr; KVBLK=32.
// LDS holds ONLY K (2x16KB dbuf, gload_lds w/ swizzled source, prefetch 1 tile ahead).
// PV B-frags are single 16B GLOBAL loads from the permuted vtg (L2-resident) -> the
// LDS pipe (was the bottleneck: ~160KB/blk-iter + 4-way b64 conflicts) drops to
// 80KB/blk-iter conflict-free, V traffic moves to the parallel L1/L2 pipe.
__global__ __launch_bounds__(256, 4) void attn7(const short* __restrict__ q,
                                                const short* __restrict__ kc,
                                                const short* __restrict__ vtg,
                                                short* __restrict__ out) {
  __shared__ alignas(16) short ks[2][32 * 256];  // 32KB dbuf, 512B rows, 3-bit src XOR
  int bid = blockIdx.x;
  int swz = (bid & 7) * 80 + (bid >> 3);
  int h = swz >> 5, qblk = swz & 31;
  int tid = threadIdx.x;
  int w = tid >> 6, l = tid & 63;
  int lr = l & 15, lg = l >> 4;

  const char* kch = (const char*)(kc + (size_t)h * S_LEN * HD);
  const short* vth = vtg + (size_t)h * DV * S_LEN;

  // Q frags (B operand): lane lr = q-row, pre-scaled by 2^-4
  int qrow = qblk * 64 + w * 16 + lr;
  const short* qbase = q + (size_t)qrow * Q_N + h * HD;
  bf16x8 qf[8];
#pragma unroll
  for (int kk = 0; kk < 8; ++kk) {
    bf16x8 v = *(const bf16x8*)(qbase + kk * 32 + lg * 8);
#pragma unroll
    for (int j = 0; j < 8; ++j) v[j] = f2bs(bs2f(v[j]) * 0.0625f);
    qf[kk] = v;
  }

  f32x4 acc[16] = {};      // lane lr = d-col, rows lg*4+r = q-rows
  float m = -3e38f;        // running max for q = lr
  float lsum = 0.f;

  auto stage_k = [&](int buf, int key0) {
#pragma unroll
    for (int p = 0; p < 4; ++p) {
      int c = p * 256 + tid;
      int row = c >> 5;
      int sb = ((c & 31) * 16) ^ ((row & 7) << 4);
      gload16(kch + (size_t)(key0 + row) * 512 + sb, (char*)ks[buf] + c * 16);
    }
  };

  stage_k(0, 0);
  WAIT_VM0();
  __builtin_amdgcn_s_barrier();

  for (int kb = 0; kb < S_LEN / 32; ++kb) {
    int cur = kb & 1;
    int key0 = kb * 32;
    if (kb + 1 < S_LEN / 32) stage_k(cur ^ 1, key0 + 32);  // async K prefetch

    // early V loads for t=0..3 (hide L2 latency under QK^T + softmax)
    bf16x8 vf_pre[4];
#pragma unroll
    for (int t = 0; t < 4; ++t)
      vf_pre[t] = *(const bf16x8*)(vth + (size_t)(t * 16 + lr) * S_LEN + key0 + lg * 8);

    // ---- QK^T swapped: s0 rows = keys 0..15, s1 rows = keys 16..31; col = q ----
    f32x4 s0 = {}, s1 = {};
    __builtin_amdgcn_s_setprio(1);
#pragma unroll
    for (int kk = 0; kk < 8; ++kk) {
      int cb = kk * 64 + lg * 16;
      int sw = (lr & 7) << 4;
      bf16x8 k0 = *(const bf16x8*)((const char*)ks[cur] + lr * 512 + (cb ^ sw));
      bf16x8 k1 = *(const bf16x8*)((const char*)ks[cur] + (16 + lr) * 512 + (cb ^ sw));
      s0 = __builtin_amdgcn_mfma_f32_16x16x32_bf16(k0, qf[kk], s0, 0, 0, 0);
      s1 = __builtin_amdgcn_mfma_f32_16x16x32_bf16(k1, qf[kk], s1, 0, 0, 0);
    }
    __builtin_amdgcn_s_setprio(0);

    // ---- softmax (all 8 scores belong to q = lr) ----
    float mx = fmaxf(fmaxf(fmaxf(s0[0], s0[1]), fmaxf(s0[2], s0[3])),
                     fmaxf(fmaxf(s1[0], s1[1]), fmaxf(s1[2], s1[3])));
    mx = fmaxf(mx, __shfl_xor(mx, 16));
    mx = fmaxf(mx, __shfl_xor(mx, 32));
    bool grow = mx > m + 8.f;
    if (__any((int)grow)) {
      float mn = fmaxf(m, mx);
      float co = __expf(m - mn);
      m = mn;
      lsum *= co;
      float c0 = __shfl(co, (l & 48) | (lg * 4 + 0));
      float c1 = __shfl(co, (l & 48) | (lg * 4 + 1));
      float c2 = __shfl(co, (l & 48) | (lg * 4 + 2));
      float c3 = __shfl(co, (l & 48) | (lg * 4 + 3));
#pragma unroll
      for (int t = 0; t < 16; ++t) {
        acc[t][0] *= c0; acc[t][1] *= c1; acc[t][2] *= c2; acc[t][3] *= c3;
      }
    }
    float e0 = __expf(s0[0] - m), e1 = __expf(s0[1] - m);
    float e2 = __expf(s0[2] - m), e3 = __expf(s0[3] - m);
    float e4 = __expf(s1[0] - m), e5 = __expf(s1[1] - m);
    float e6 = __expf(s1[2] - m), e7 = __expf(s1[3] - m);
    float ts = ((e0 + e1) + (e2 + e3)) + ((e4 + e5) + (e6 + e7));
    ts += __shfl_xor(ts, 16);
    ts += __shfl_xor(ts, 32);
    lsum += ts;
    bf16x8 pa;
    pa[0] = f2bs(e0); pa[1] = f2bs(e1); pa[2] = f2bs(e2); pa[3] = f2bs(e3);
    pa[4] = f2bs(e4); pa[5] = f2bs(e5); pa[6] = f2bs(e6); pa[7] = f2bs(e7);

    // ---- PV: acc[t] += P(A) * V(B); B-frag = single 16B global load (permuted vtg) ----
    __builtin_amdgcn_s_setprio(1);
#pragma unroll
    for (int t = 0; t < 4; ++t)
      acc[t] = __builtin_amdgcn_mfma_f32_16x16x32_bf16(pa, vf_pre[t], acc[t], 0, 0, 0);
#pragma unroll
    for (int t = 4; t < 16; ++t) {
      bf16x8 vf = *(const bf16x8*)(vth + (size_t)(t * 16 + lr) * S_LEN + key0 + lg * 8);
      acc[t] = __builtin_amdgcn_mfma_f32_16x16x32_bf16(pa, vf, acc[t], 0, 0, 0);
    }
    __builtin_amdgcn_s_setprio(0);

    WAIT_VM0();                     // K prefetch landed (issued at iter top -> ~free)
    __builtin_amdgcn_s_barrier();   // all waves done reading ks[cur]; ks[cur^1] ready
  }

  float inv = 1.f / lsum;  // valid for q = lr
  float i0 = __shfl(inv, (l & 48) | (lg * 4 + 0));
  float i1 = __shfl(inv, (l & 48) | (lg * 4 + 1));
  float i2 = __shfl(inv, (l & 48) | (lg * 4 + 2));
  float i3 = __shfl(inv, (l & 48) | (lg * 4 + 3));
#pragma unroll
  for (int t = 0; t < 16; ++t) {
    int row = qblk * 64 + w * 16 + lg * 4;
    int col = h * DV + t * 16 + lr;
    out[(size_t)(row + 0) * O_N + col] = f2bs(acc[t][0] * i0);
    out[(size_t)(row + 1) * O_N + col] = f2bs(acc[t][1] * i1);
    out[(size_t)(row + 2) * O_N + col] = f2bs(acc[t][2] * i2);
    out[(size_t)(row + 3) * O_N + col] = f2bs(acc[t][3] * i3);
  }
}

extern "C" void kernel_launch(void* const* d_in, const int* in_sizes, int n_in,
                              void* d_out, int out_size, void* d_ws, size_t ws_size,
                              hipStream_t stream) {
  const float* x       = (const float*)d_in[0];
  const int*   pos     = (const int*)d_in[1];
  const float* q_a_w   = (const float*)d_in[2];
  const float* q_b_w   = (const float*)d_in[3];
  const float* kv_a_w  = (const float*)d_in[4];
  const float* kv_b_w  = (const float*)d_in[5];
  const float* o_w     = (const float*)d_in[6];
  const float* q_a_ln  = (const float*)d_in[7];
  const float* kv_a_ln = (const float*)d_in[8];
  float* out = (float*)d_out;

  char* p = (char*)d_ws;
  auto alloc = [&](size_t bytes) {
    char* r = p;
    p += (bytes + 255) & ~(size_t)255;
    return r;
  };
  short* xb    = (short*)alloc((size_t)S_LEN * HID * 2);
  short* wcat  = (short*)alloc((size_t)QKVA * HID * 2);   // q_a_w ‖ kv_a_w(padded)
  short* qbw   = (short*)alloc((size_t)Q_N * QR * 2);
  short* kvbw  = (short*)alloc((size_t)KV_N * KVR * 2);
  short* ow    = (short*)alloc((size_t)HID * O_N * 2);
  float* qkv   = (float*)alloc((size_t)S_LEN * QKVA * 4); // fused a-proj out
  short* q_ln  = (short*)alloc((size_t)S_LEN * QR * 2);
  short* qbuf  = (short*)alloc((size_t)S_LEN * Q_N * 2);
  short* kv_ln = (short*)alloc((size_t)S_LEN * KVR * 2);
  short* kvx   = (short*)alloc((size_t)S_LEN * KV_N * 2);
  short* kr    = (short*)alloc((size_t)S_LEN * 64 * 2);
  float* ct    = (float*)alloc((size_t)S_LEN * 32 * 4);
  float* st    = (float*)alloc((size_t)S_LEN * 32 * 4);
  short* ao    = (short*)alloc((size_t)S_LEN * O_N * 2);
  short* kcb   = (short*)alloc((size_t)NH * S_LEN * HD * 2);
  short* vtg   = (short*)alloc((size_t)NH * DV * S_LEN * 2);
  (void)ws_size; (void)n_in; (void)in_sizes; (void)out_size;

  auto cvt = [&](const float* in, short* o, size_t n) {
    size_t blocks = (n + 255) / 256;
    if (blocks > 2048) blocks = 2048;
    f2b_kernel<<<dim3((unsigned)blocks), dim3(256), 0, stream>>>(in, o, n);
  };
  cvt(x, xb, (size_t)S_LEN * HID);
  cvt(q_a_w, wcat, (size_t)QR * HID);
  cvt(kv_a_w, wcat + (size_t)QR * HID, (size_t)KVA_N * HID);
  hipMemsetAsync(wcat + (size_t)(QR + KVA_N) * HID, 0, (size_t)(KVAP - KVA_N) * HID * 2, stream);
  cvt(q_b_w, qbw, (size_t)Q_N * QR);
  cvt(kv_b_w, kvbw, (size_t)KV_N * KVR);
  cvt(o_w, ow, (size_t)HID * O_N);

  dim3 blk(256);
  // fused a-proj: qkv[S][1408] = x @ [q_a_w ‖ kv_a_w]^T
  gemm64<<<dim3(QKVA / 128, S_LEN / 64), blk, 0, stream>>>(xb, wcat, qkv, S_LEN, QKVA, HID);
  // rmsnorms -> bf16
  rmsnorm_kernel<<<dim3(S_LEN), blk, 0, stream>>>(qkv, q_a_ln, q_ln, QR, QKVA, QR);
  rmsnorm_kernel<<<dim3(S_LEN), blk, 0, stream>>>(qkv + QR, kv_a_ln, kv_ln, KVR, QKVA, KVR);
  // up-projections -> bf16
  gemm128<1><<<dim3(Q_N / 128, S_LEN / 128), blk, 0, stream>>>(q_ln, qbw, qbuf, S_LEN, Q_N, QR);
  gemm128<1><<<dim3(KV_N / 128, S_LEN / 128), blk, 0, stream>>>(kv_ln, kvbw, kvx, S_LEN, KV_N, KVR);
  // rope
  rope_table_kernel<<<dim3(S_LEN / 256), blk, 0, stream>>>(pos, ct, st);
  rope_q_kernel<<<dim3((S_LEN * NH + 255) / 256), blk, 0, stream>>>(qbuf, ct, st);
  rope_k_kernel<<<dim3(S_LEN / 256), blk, 0, stream>>>(qkv + QR + KVR, ct, st, kr);
  // per-head contiguous K and permuted-transposed V
  kc_build<<<dim3(NH * S_LEN * 32 / 256), blk, 0, stream>>>(kvx, kr, kcb);
  vtrans<<<dim3(S_LEN / 64, DV / 64, NH), blk, 0, stream>>>(kvx, vtg);
  // fused attention
  attn7<<<dim3(NH * S_LEN / 64), blk, 0, stream>>>(qbuf, kcb, vtg, ao);
  // output projection (fp32 out)
  gemm128<0><<<dim3(HID / 128, S_LEN / 128), blk, 0, stream>>>(ao, ow, out, S_LEN, HID, O_N);
}

// Round 9
// 451.238 us; speedup vs baseline: 1.7212x; 1.7212x over previous
//
#include <hip/hip_runtime.h>
#include <hip/hip_bf16.h>

#define HID 2048
#define NH 20
#define QR 768
#define KVR 512
#define DN 192
#define DR 64
#define DV 256
#define HD 256          // HEAD_DIM = DN + DR
#define S_LEN 2048
#define HKV 448         // DN + DV
#define KV_N (NH * HKV) // 8960
#define Q_N (NH * HD)   // 5120
#define O_N (NH * DV)   // 5120
#define KVA_N (KVR + DR) // 576
#define KVAP 640         // padded kv_a rows
#define QKVA (QR + KVAP) // 1408 fused a-proj cols

typedef short bf16x8 __attribute__((ext_vector_type(8)));
typedef short bf16x4 __attribute__((ext_vector_type(4)));
typedef float f32x4 __attribute__((ext_vector_type(4)));

__device__ inline short f2bs(float f) {
  __hip_bfloat16 h = __float2bfloat16(f);
  return *reinterpret_cast<short*>(&h);
}
__device__ inline float bs2f(short s) {
  __hip_bfloat16 h = *reinterpret_cast<__hip_bfloat16*>(&s);
  return __bfloat162float(h);
}

__device__ inline void gload16(const void* g, void* l) {
  __builtin_amdgcn_global_load_lds((const __attribute__((address_space(1))) void*)g,
                                   (__attribute__((address_space(3))) void*)l, 16, 0, 0);
}

#define WAIT_LGKM0() asm volatile("s_waitcnt lgkmcnt(0)" ::: "memory")
#define WAIT_VM0() asm volatile("s_waitcnt vmcnt(0)" ::: "memory")

// ---------------- fp32 -> bf16 convert ----------------
__global__ void f2b_kernel(const float* __restrict__ in, short* __restrict__ out, size_t n) {
  size_t i = (size_t)blockIdx.x * blockDim.x + threadIdx.x;
  size_t stride = (size_t)gridDim.x * blockDim.x;
  for (; i < n; i += stride) out[i] = f2bs(in[i]);
}

// ---------------- big GEMM: 128x128 tile, BK=64, global_load_lds + XOR swizzle ----------------
template <int OUT_BF16>
__global__ __launch_bounds__(256) void gemm128(const short* __restrict__ A,
                                               const short* __restrict__ B,
                                               void* __restrict__ Cp,
                                               int M, int N, int K) {
  __shared__ alignas(16) short As[128 * 64];
  __shared__ alignas(16) short Bs[128 * 64];
  int tid = threadIdx.x;
  int w = tid >> 6, l = tid & 63;
  int lr = l & 15, lg = l >> 4;
  int wr = w >> 1, wc = w & 1;
  int row0 = blockIdx.y * 128, col0 = blockIdx.x * 128;
  f32x4 acc[4][4] = {};
  for (int k0 = 0; k0 < K; k0 += 64) {
    if (k0) __syncthreads();
#pragma unroll
    for (int p = 0; p < 4; ++p) {
      int c = p * 256 + tid;
      int row = c >> 3;
      int sb = ((c & 7) * 16) ^ ((row & 7) << 4);
      gload16((const char*)A + ((size_t)(row0 + row) * K + k0) * 2 + sb, (char*)As + c * 16);
      gload16((const char*)B + ((size_t)(col0 + row) * K + k0) * 2 + sb, (char*)Bs + c * 16);
    }
    __syncthreads();
    bf16x8 af[4][2], bf[4][2];
#pragma unroll
    for (int m = 0; m < 4; ++m)
#pragma unroll
      for (int kk = 0; kk < 2; ++kk) {
        int ra = wr * 64 + m * 16 + lr;
        int rb = wc * 64 + m * 16 + lr;
        int cb = kk * 64 + lg * 16;
        af[m][kk] = *(const bf16x8*)((const char*)As + ra * 128 + (cb ^ ((ra & 7) << 4)));
        bf[m][kk] = *(const bf16x8*)((const char*)Bs + rb * 128 + (cb ^ ((rb & 7) << 4)));
      }
#pragma unroll
    for (int m = 0; m < 4; ++m)
#pragma unroll
      for (int n = 0; n < 4; ++n) {
        acc[m][n] = __builtin_amdgcn_mfma_f32_16x16x32_bf16(af[m][0], bf[n][0], acc[m][n], 0, 0, 0);
        acc[m][n] = __builtin_amdgcn_mfma_f32_16x16x32_bf16(af[m][1], bf[n][1], acc[m][n], 0, 0, 0);
      }
  }
#pragma unroll
  for (int m = 0; m < 4; ++m)
#pragma unroll
    for (int n = 0; n < 4; ++n)
#pragma unroll
      for (int r = 0; r < 4; ++r) {
        int row = row0 + wr * 64 + m * 16 + lg * 4 + r;
        int col = col0 + wc * 64 + n * 16 + lr;
        if (OUT_BF16)
          ((short*)Cp)[(size_t)row * N + col] = f2bs(acc[m][n][r]);
        else
          ((float*)Cp)[(size_t)row * N + col] = acc[m][n][r];
      }
}

// ---------------- medium GEMM: 64x128 tile (for wide-short shapes) ----------------
__global__ __launch_bounds__(256) void gemm64(const short* __restrict__ A,
                                              const short* __restrict__ B,
                                              float* __restrict__ C,
                                              int M, int N, int K) {
  __shared__ alignas(16) short As[64 * 64];    // 8KB
  __shared__ alignas(16) short Bs[128 * 64];   // 16KB
  int tid = threadIdx.x;
  int w = tid >> 6, l = tid & 63;
  int lr = l & 15, lg = l >> 4;
  int wr = w >> 1, wc = w & 1;
  int row0 = blockIdx.y * 64, col0 = blockIdx.x * 128;
  f32x4 acc[2][4] = {};
  for (int k0 = 0; k0 < K; k0 += 64) {
    if (k0) __syncthreads();
#pragma unroll
    for (int p = 0; p < 2; ++p) {
      int c = p * 256 + tid;
      int row = c >> 3;
      int sb = ((c & 7) * 16) ^ ((row & 7) << 4);
      gload16((const char*)A + ((size_t)(row0 + row) * K + k0) * 2 + sb, (char*)As + c * 16);
    }
#pragma unroll
    for (int p = 0; p < 4; ++p) {
      int c = p * 256 + tid;
      int row = c >> 3;
      int sb = ((c & 7) * 16) ^ ((row & 7) << 4);
      gload16((const char*)B + ((size_t)(col0 + row) * K + k0) * 2 + sb, (char*)Bs + c * 16);
    }
    __syncthreads();
    bf16x8 af[2][2], bf[4][2];
#pragma unroll
    for (int m = 0; m < 2; ++m)
#pragma unroll
      for (int kk = 0; kk < 2; ++kk) {
        int ra = wr * 32 + m * 16 + lr;
        int cb = kk * 64 + lg * 16;
        af[m][kk] = *(const bf16x8*)((const char*)As + ra * 128 + (cb ^ ((ra & 7) << 4)));
      }
#pragma unroll
    for (int n = 0; n < 4; ++n)
#pragma unroll
      for (int kk = 0; kk < 2; ++kk) {
        int rb = wc * 64 + n * 16 + lr;
        int cb = kk * 64 + lg * 16;
        bf[n][kk] = *(const bf16x8*)((const char*)Bs + rb * 128 + (cb ^ ((rb & 7) << 4)));
      }
#pragma unroll
    for (int m = 0; m < 2; ++m)
#pragma unroll
      for (int n = 0; n < 4; ++n) {
        acc[m][n] = __builtin_amdgcn_mfma_f32_16x16x32_bf16(af[m][0], bf[n][0], acc[m][n], 0, 0, 0);
        acc[m][n] = __builtin_amdgcn_mfma_f32_16x16x32_bf16(af[m][1], bf[n][1], acc[m][n], 0, 0, 0);
      }
  }
#pragma unroll
  for (int m = 0; m < 2; ++m)
#pragma unroll
    for (int n = 0; n < 4; ++n)
#pragma unroll
      for (int r = 0; r < 4; ++r) {
        int row = row0 + wr * 32 + m * 16 + lg * 4 + r;
        int col = col0 + wc * 64 + n * 16 + lr;
        C[(size_t)row * N + col] = acc[m][n][r];
      }
}

// ---------------- rmsnorm (fp32 in, bf16 out) ----------------
__global__ __launch_bounds__(256) void rmsnorm_kernel(const float* __restrict__ in,
                                                      const float* __restrict__ w,
                                                      short* __restrict__ out,
                                                      int N, int in_stride, int out_stride) {
  int row = blockIdx.x;
  const float* x = in + (size_t)row * in_stride;
  float ss = 0.f;
  for (int i = threadIdx.x; i < N; i += 256) { float v = x[i]; ss += v * v; }
#pragma unroll
  for (int off = 32; off >= 1; off >>= 1) ss += __shfl_down(ss, off);
  __shared__ float red[4];
  if ((threadIdx.x & 63) == 0) red[threadIdx.x >> 6] = ss;
  __syncthreads();
  float tot = red[0] + red[1] + red[2] + red[3];
  float sc = rsqrtf(tot / (float)N + 1e-5f);
  short* o = out + (size_t)row * out_stride;
  for (int i = threadIdx.x; i < N; i += 256) o[i] = f2bs(x[i] * sc * w[i]);
}

// ---------------- rope tables ----------------
__global__ void rope_table_kernel(const int* __restrict__ pos, float* __restrict__ ct,
                                  float* __restrict__ st) {
  int s = blockIdx.x * blockDim.x + threadIdx.x;
  if (s >= S_LEN) return;
  double p = (double)pos[s];
  for (int d = 0; d < 32; ++d) {
    double invf = exp(-((double)(2 * d) / 64.0) * log(1.0e6));
    double a = p * invf;
    ct[s * 32 + d] = (float)cos(a);
    st[s * 32 + d] = (float)sin(a);
  }
}

// ---------------- rope applied in-place to q's rope slice ----------------
__global__ void rope_q_kernel(short* __restrict__ q, const float* __restrict__ ct,
                              const float* __restrict__ st) {
  int idx = blockIdx.x * blockDim.x + threadIdx.x;
  if (idx >= S_LEN * NH) return;
  int s = idx / NH, h = idx % NH;
  short* p = q + (size_t)s * Q_N + h * HD + DN;
  float x[64];
#pragma unroll
  for (int i = 0; i < 64; ++i) x[i] = bs2f(p[i]);
  const float* c = ct + s * 32;
  const float* sn = st + s * 32;
#pragma unroll
  for (int d = 0; d < 32; ++d) {
    float x1 = x[2 * d], x2 = x[2 * d + 1];
    p[d] = f2bs(x1 * c[d] - x2 * sn[d]);
    p[32 + d] = f2bs(x1 * sn[d] + x2 * c[d]);
  }
}

// ---------------- rope for shared k_rope (reads fused qkv buffer) ----------------
__global__ void rope_k_kernel(const float* __restrict__ base, const float* __restrict__ ct,
                              const float* __restrict__ st, short* __restrict__ kr) {
  int s = blockIdx.x * blockDim.x + threadIdx.x;
  if (s >= S_LEN) return;
  const float* x = base + (size_t)s * QKVA;
  const float* c = ct + s * 32;
  const float* sn = st + s * 32;
  short* o = kr + s * 64;
#pragma unroll
  for (int d = 0; d < 32; ++d) {
    float x1 = x[2 * d], x2 = x[2 * d + 1];
    o[d] = f2bs(x1 * c[d] - x2 * sn[d]);
    o[32 + d] = f2bs(x1 * sn[d] + x2 * c[d]);
  }
}

// ---------------- build Kc[h][s][256] = k_nope ‖ roped k_rope ----------------
__global__ void kc_build(const short* __restrict__ kvx, const short* __restrict__ kr,
                         short* __restrict__ kc) {
  int idx = blockIdx.x * 256 + threadIdx.x;
  int h = idx >> 16;
  int r = idx & 65535;
  int s = r >> 5, c = r & 31;
  const short* src = (c < 24) ? kvx + (size_t)s * KV_N + h * HKV + c * 8
                              : kr + (size_t)s * 64 + (c - 24) * 8;
  *(bf16x8*)(kc + ((size_t)h * S_LEN + s) * HD + c * 8) = *(const bf16x8*)src;
}

// ---------------- transpose V with PV-key permutation + slot-XOR: vtg[h][d][key-perm] ----------------
// kappa(p): position p holds key (p&4) ? 16+(p>>3)*4+(p&3) : (p>>3)*4+(p&3)  [R8-verified],
// then the 16B slot (p>>3) is XORed with s(d) = ((d&15)>>1)&3 so the in-LDS PV
// ds_read_b128 (slot = lg ^ s) is exactly 8 accesses/bank = conflict-free.
__global__ __launch_bounds__(256) void vtrans(const short* __restrict__ kvx,
                                              short* __restrict__ vtg) {
  __shared__ short tile[64][65];
  int s0 = blockIdx.x * 64, d0 = blockIdx.y * 64, h = blockIdx.z;
  int tid = threadIdx.x;
#pragma unroll
  for (int p = 0; p < 2; ++p) {
    int s = p * 32 + (tid >> 3), dc = (tid & 7) * 8;
    bf16x8 v = *(const bf16x8*)(kvx + (size_t)(s0 + s) * KV_N + h * HKV + DN + d0 + dc);
#pragma unroll
    for (int j = 0; j < 8; ++j) tile[s][dc + j] = v[j];
  }
  __syncthreads();
#pragma unroll
  for (int p = 0; p < 2; ++p) {
    int d = p * 32 + (tid >> 3), sc = (tid & 7) * 8;
    bf16x4 a, b;
#pragma unroll
    for (int j = 0; j < 4; ++j) a[j] = tile[sc + j][d];
#pragma unroll
    for (int j = 0; j < 4; ++j) b[j] = tile[sc + 4 + j][d];
    int q1 = sc & 31, q2 = q1 + 4;
    int p1 = (q1 < 16) ? (q1 >> 2) * 8 : ((q1 - 16) >> 2) * 8 + 4;
    int p2 = (q2 < 16) ? (q2 >> 2) * 8 : ((q2 - 16) >> 2) * 8 + 4;
    int s = ((d & 15) >> 1) & 3;  // slot-XOR key (d0 is a multiple of 64 -> d&15 == dfull&15)
    p1 = ((((p1 >> 3) ^ s)) << 3) | (p1 & 7);
    p2 = ((((p2 >> 3) ^ s)) << 3) | (p2 & 7);
    size_t rowbase = ((size_t)h * DV + d0 + d) * S_LEN + s0 + (sc & ~31);
    *(bf16x4*)(vtg + rowbase + p1) = a;
    *(bf16x4*)(vtg + rowbase + p2) = b;
  }
}

// ---------------- fused flash attention v8: swapped QK^T + full K/V LDS double-buffer ----------------
// grid = 640 (XCD-swizzled); 256 thr; KVBLK=32; LDS 64KB -> 2 blocks/CU.
// ALL 8 gload_lds for tile t+1 issue at the TOP of iter t -> vmcnt(0) at the bottom has
// a full iteration (~1100cy >> L2 latency) in flight = ~free. ONE barrier per iter.
// V tile permuted+slot-XORed in vtg -> PV ds_read_b128 conflict-free; K read 2-way (free).
__global__ __launch_bounds__(256, 4) void attn8(const short* __restrict__ q,
                                                const short* __restrict__ kc,
                                                const short* __restrict__ vtg,
                                                short* __restrict__ out) {
  __shared__ alignas(16) short ks[2][32 * 256];  // 32KB, 512B rows, 3-bit src XOR
  __shared__ alignas(16) short vt[2][256 * 32];  // 32KB, vt[d][key-perm], 64B rows
  int bid = blockIdx.x;
  int swz = (bid & 7) * 80 + (bid >> 3);
  int h = swz >> 5, qblk = swz & 31;
  int tid = threadIdx.x;
  int w = tid >> 6, l = tid & 63;
  int lr = l & 15, lg = l >> 4;

  const char* kch = (const char*)(kc + (size_t)h * S_LEN * HD);
  const short* vth = vtg + (size_t)h * DV * S_LEN;

  // Q frags (B operand): lane lr = q-row, pre-scaled by 2^-4
  int qrow = qblk * 64 + w * 16 + lr;
  const short* qbase = q + (size_t)qrow * Q_N + h * HD;
  bf16x8 qf[8];
#pragma unroll
  for (int kk = 0; kk < 8; ++kk) {
    bf16x8 v = *(const bf16x8*)(qbase + kk * 32 + lg * 8);
#pragma unroll
    for (int j = 0; j < 8; ++j) v[j] = f2bs(bs2f(v[j]) * 0.0625f);
    qf[kk] = v;
  }

  f32x4 acc[16] = {};      // lane lr = d-col, rows lg*4+r = q-rows
  float m = -3e38f;        // running max for q = lr
  float lsum = 0.f;

  auto stage_k = [&](int buf, int key0) {
#pragma unroll
    for (int p = 0; p < 4; ++p) {
      int c = p * 256 + tid;
      int row = c >> 5;
      int sb = ((c & 31) * 16) ^ ((row & 7) << 4);
      gload16(kch + (size_t)(key0 + row) * 512 + sb, (char*)ks[buf] + c * 16);
    }
  };
  auto stage_v = [&](int buf, int key0) {
#pragma unroll
    for (int p = 0; p < 4; ++p) {
      int c = p * 256 + tid;
      int d = c >> 2, slot = c & 3;
      gload16(vth + (size_t)d * S_LEN + key0 + slot * 8, (char*)vt[buf] + c * 16);
    }
  };

  // prologue: stage tile 0, drain, barrier
  stage_k(0, 0);
  stage_v(0, 0);
  WAIT_VM0();
  __builtin_amdgcn_s_barrier();

  int sxor = (lr >> 1) & 3;  // PV slot-XOR key (lane-constant)

  for (int kb = 0; kb < S_LEN / 32; ++kb) {
    int cur = kb & 1;
    int key0 = kb * 32;
    if (kb + 1 < S_LEN / 32) {          // prefetch tile t+1 (8 vm ops, in flight all iter)
      stage_k(cur ^ 1, key0 + 32);
      stage_v(cur ^ 1, key0 + 32);
    }

    // ---- QK^T swapped: s0 rows = keys 0..15, s1 rows = keys 16..31; col = q ----
    f32x4 s0 = {}, s1 = {};
    __builtin_amdgcn_s_setprio(1);
#pragma unroll
    for (int kk = 0; kk < 8; ++kk) {
      int cb = kk * 64 + lg * 16;
      int sw = (lr & 7) << 4;
      bf16x8 k0 = *(const bf16x8*)((const char*)ks[cur] + lr * 512 + (cb ^ sw));
      bf16x8 k1 = *(const bf16x8*)((const char*)ks[cur] + (16 + lr) * 512 + (cb ^ sw));
      s0 = __builtin_amdgcn_mfma_f32_16x16x32_bf16(k0, qf[kk], s0, 0, 0, 0);
      s1 = __builtin_amdgcn_mfma_f32_16x16x32_bf16(k1, qf[kk], s1, 0, 0, 0);
    }
    __builtin_amdgcn_s_setprio(0);

    // ---- softmax (all 8 scores belong to q = lr) ----
    float mx = fmaxf(fmaxf(fmaxf(s0[0], s0[1]), fmaxf(s0[2], s0[3])),
                     fmaxf(fmaxf(s1[0], s1[1]), fmaxf(s1[2], s1[3])));
    mx = fmaxf(mx, __shfl_xor(mx, 16));
    mx = fmaxf(mx, __shfl_xor(mx, 32));
    bool grow = mx > m + 8.f;
    if (__any((int)grow)) {
      float mn = fmaxf(m, mx);
      float co = __expf(m - mn);
      m = mn;
      lsum *= co;
      float c0 = __shfl(co, (l & 48) | (lg * 4 + 0));
      float c1 = __shfl(co, (l & 48) | (lg * 4 + 1));
      float c2 = __shfl(co, (l & 48) | (lg * 4 + 2));
      float c3 = __shfl(co, (l & 48) | (lg * 4 + 3));
#pragma unroll
      for (int t = 0; t < 16; ++t) {
        acc[t][0] *= c0; acc[t][1] *= c1; acc[t][2] *= c2; acc[t][3] *= c3;
      }
    }
    float e0 = __expf(s0[0] - m), e1 = __expf(s0[1] - m);
    float e2 = __expf(s0[2] - m), e3 = __expf(s0[3] - m);
    float e4 = __expf(s1[0] - m), e5 = __expf(s1[1] - m);
    float e6 = __expf(s1[2] - m), e7 = __expf(s1[3] - m);
    float ts = ((e0 + e1) + (e2 + e3)) + ((e4 + e5) + (e6 + e7));
    ts += __shfl_xor(ts, 16);
    ts += __shfl_xor(ts, 32);
    lsum += ts;
    bf16x8 pa;
    pa[0] = f2bs(e0); pa[1] = f2bs(e1); pa[2] = f2bs(e2); pa[3] = f2bs(e3);
    pa[4] = f2bs(e4); pa[5] = f2bs(e5); pa[6] = f2bs(e6); pa[7] = f2bs(e7);

    // ---- PV: acc[t] += P(A) * V(B); B-frag = one conflict-free ds_read_b128 ----
    __builtin_amdgcn_s_setprio(1);
#pragma unroll
    for (int t = 0; t < 16; ++t) {
      int d = t * 16 + lr;
      bf16x8 vf = *(const bf16x8*)((const char*)vt[cur] + d * 64 + ((lg ^ sxor) << 4));
      acc[t] = __builtin_amdgcn_mfma_f32_16x16x32_bf16(pa, vf, acc[t], 0, 0, 0);
    }
    __builtin_amdgcn_s_setprio(0);

    WAIT_VM0();                     // t+1 stages: issued a full iteration ago -> ~free
    __builtin_amdgcn_s_barrier();   // single barrier: buffers flip
  }

  float inv = 1.f / lsum;  // valid for q = lr
  float i0 = __shfl(inv, (l & 48) | (lg * 4 + 0));
  float i1 = __shfl(inv, (l & 48) | (lg * 4 + 1));
  float i2 = __shfl(inv, (l & 48) | (lg * 4 + 2));
  float i3 = __shfl(inv, (l & 48) | (lg * 4 + 3));
#pragma unroll
  for (int t = 0; t < 16; ++t) {
    int row = qblk * 64 + w * 16 + lg * 4;
    int col = h * DV + t * 16 + lr;
    out[(size_t)(row + 0) * O_N + col] = f2bs(acc[t][0] * i0);
    out[(size_t)(row + 1) * O_N + col] = f2bs(acc[t][1] * i1);
    out[(size_t)(row + 2) * O_N + col] = f2bs(acc[t][2] * i2);
    out[(size_t)(row + 3) * O_N + col] = f2bs(acc[t][3] * i3);
  }
}

extern "C" void kernel_launch(void* const* d_in, const int* in_sizes, int n_in,
                              void* d_out, int out_size, void* d_ws, size_t ws_size,
                              hipStream_t stream) {
  const float* x       = (const float*)d_in[0];
  const int*   pos     = (const int*)d_in[1];
  const float* q_a_w   = (const float*)d_in[2];
  const float* q_b_w   = (const float*)d_in[3];
  const float* kv_a_w  = (const float*)d_in[4];
  const float* kv_b_w  = (const float*)d_in[5];
  const float* o_w     = (const float*)d_in[6];
  const float* q_a_ln  = (const float*)d_in[7];
  const float* kv_a_ln = (const float*)d_in[8];
  float* out = (float*)d_out;

  char* p = (char*)d_ws;
  auto alloc = [&](size_t bytes) {
    char* r = p;
    p += (bytes + 255) & ~(size_t)255;
    return r;
  };
  short* xb    = (short*)alloc((size_t)S_LEN * HID * 2);
  short* wcat  = (short*)alloc((size_t)QKVA * HID * 2);   // q_a_w ‖ kv_a_w(padded)
  short* qbw   = (short*)alloc((size_t)Q_N * QR * 2);
  short* kvbw  = (short*)alloc((size_t)KV_N * KVR * 2);
  short* ow    = (short*)alloc((size_t)HID * O_N * 2);
  float* qkv   = (float*)alloc((size_t)S_LEN * QKVA * 4); // fused a-proj out
  short* q_ln  = (short*)alloc((size_t)S_LEN * QR * 2);
  short* qbuf  = (short*)alloc((size_t)S_LEN * Q_N * 2);
  short* kv_ln = (short*)alloc((size_t)S_LEN * KVR * 2);
  short* kvx   = (short*)alloc((size_t)S_LEN * KV_N * 2);
  short* kr    = (short*)alloc((size_t)S_LEN * 64 * 2);
  float* ct    = (float*)alloc((size_t)S_LEN * 32 * 4);
  float* st    = (float*)alloc((size_t)S_LEN * 32 * 4);
  short* ao    = (short*)alloc((size_t)S_LEN * O_N * 2);
  short* kcb   = (short*)alloc((size_t)NH * S_LEN * HD * 2);
  short* vtg   = (short*)alloc((size_t)NH * DV * S_LEN * 2);
  (void)ws_size; (void)n_in; (void)in_sizes; (void)out_size;

  auto cvt = [&](const float* in, short* o, size_t n) {
    size_t blocks = (n + 255) / 256;
    if (blocks > 2048) blocks = 2048;
    f2b_kernel<<<dim3((unsigned)blocks), dim3(256), 0, stream>>>(in, o, n);
  };
  cvt(x, xb, (size_t)S_LEN * HID);
  cvt(q_a_w, wcat, (size_t)QR * HID);
  cvt(kv_a_w, wcat + (size_t)QR * HID, (size_t)KVA_N * HID);
  hipMemsetAsync(wcat + (size_t)(QR + KVA_N) * HID, 0, (size_t)(KVAP - KVA_N) * HID * 2, stream);
  cvt(q_b_w, qbw, (size_t)Q_N * QR);
  cvt(kv_b_w, kvbw, (size_t)KV_N * KVR);
  cvt(o_w, ow, (size_t)HID * O_N);

  dim3 blk(256);
  // fused a-proj: qkv[S][1408] = x @ [q_a_w ‖ kv_a_w]^T
  gemm64<<<dim3(QKVA / 128, S_LEN / 64), blk, 0, stream>>>(xb, wcat, qkv, S_LEN, QKVA, HID);
  // rmsnorms -> bf16
  rmsnorm_kernel<<<dim3(S_LEN), blk, 0, stream>>>(qkv, q_a_ln, q_ln, QR, QKVA, QR);
  rmsnorm_kernel<<<dim3(S_LEN), blk, 0, stream>>>(qkv + QR, kv_a_ln, kv_ln, KVR, QKVA, KVR);
  // up-projections -> bf16
  gemm128<1><<<dim3(Q_N / 128, S_LEN / 128), blk, 0, stream>>>(q_ln, qbw, qbuf, S_LEN, Q_N, QR);
  gemm128<1><<<dim3(KV_N / 128, S_LEN / 128), blk, 0, stream>>>(kv_ln, kvbw, kvx, S_LEN, KV_N, KVR);
  // rope
  rope_table_kernel<<<dim3(S_LEN / 256), blk, 0, stream>>>(pos, ct, st);
  rope_q_kernel<<<dim3((S_LEN * NH + 255) / 256), blk, 0, stream>>>(qbuf, ct, st);
  rope_k_kernel<<<dim3(S_LEN / 256), blk, 0, stream>>>(qkv + QR + KVR, ct, st, kr);
  // per-head contiguous K and permuted+XORed transposed V
  kc_build<<<dim3(NH * S_LEN * 32 / 256), blk, 0, stream>>>(kvx, kr, kcb);
  vtrans<<<dim3(S_LEN / 64, DV / 64, NH), blk, 0, stream>>>(kvx, vtg);
  // fused attention
  attn8<<<dim3(NH * S_LEN / 64), blk, 0, stream>>>(qbuf, kcb, vtg, ao);
  // output projection (fp32 out, 64x128 tile -> 512 blocks)
  gemm64<<<dim3(HID / 128, S_LEN / 64), blk, 0, stream>>>(ao, ow, out, S_LEN, HID, O_N);
}